// Round 15
// baseline (340.360 us; speedup 1.0000x reference)
//
#include <hip/hip_runtime.h>
#include <hip/hip_bf16.h>
#include <math.h>

#define NN 30000
#define EE 240000
#define IN_DIM 512
#define DD 128
#define OUTD 64
#define NV 2
#define NBLK 2
#define NH 2
#define DMM 64
#define NEG_ATT 0.2f
#define NEG_OUT 0.01f
#define CH 1024
#define NCH ((NN + CH - 1) / CH)   // 30

typedef __attribute__((ext_vector_type(8))) short bf16x8;
typedef __attribute__((ext_vector_type(4))) float f32x4;
typedef __attribute__((ext_vector_type(4))) unsigned short us4;
typedef __attribute__((ext_vector_type(8))) unsigned short us8;

// weight-plane offsets (hwords)
#define OFF_PROJVM 0
#define OFF_WV     131072
#define OFF_WGM    262144
#define OFF_TRAN   278528
#define WT_TOTAL   319488

__device__ __forceinline__ unsigned short f2bf(float x) {
  unsigned u = __float_as_uint(x);
  return (unsigned short)((u + 0x7FFFu + ((u >> 16) & 1u)) >> 16);
}
__device__ __forceinline__ float bf2f(unsigned short u) {
  return __uint_as_float((unsigned)u << 16);
}
__device__ __forceinline__ void gload16(void* lds, const void* g) {
  __builtin_amdgcn_global_load_lds((const __attribute__((address_space(1))) unsigned int*)g,
                                   (__attribute__((address_space(3))) unsigned int*)lds, 16, 0, 0);
}

// auxiliary work descriptors for fused launches
struct AUX {
  const int* fsrc; const int* fdst; const int* foff; int* fcur; int* fcsr;   // edge fill
  const float *lBl0, *lBr0, *lBl1, *lBr1, *lWg0, *lWg1;                      // llr epilogue
  float4* llq; float2* llr;
};

__device__ void fill_body(int fb, int t, const AUX& a) {
  int e = fb * 256 + t;
  if (e >= NV * EE) return;
  int view = e / EE;
  int d = a.fdst[e];
  int p = atomicAdd(&a.fcur[view * NN + d], 1);
  a.fcsr[view * EE + a.foff[view * (NN + 1) + d] + p] = a.fsrc[e];
}

// ---------------- fused: deg histogram (blocks 0..1874)  ||  prepw (1875..2134) ----------------
__global__ __launch_bounds__(256) void kA_deg_prepw(const int* __restrict__ dst, int* __restrict__ deg,
                                                    const float* __restrict__ W_embed,
                                                    const float* __restrict__ a_l, const float* __restrict__ a_r,
                                                    const float* __restrict__ Wp, const float* __restrict__ Wgm,
                                                    float* __restrict__ Bl, float* __restrict__ Br,
                                                    float* __restrict__ wf) {
  int b = blockIdx.x;
  if (b < 1875) {
    int e = b * 256 + threadIdx.x;
    if (e < NV * EE) atomicAdd(&deg[(e / EE) * NN + dst[e]], 1);
    return;
  }
  int pb = b - 1875;
  if (pb < 256) {
    int idx = pb * 256 + threadIdx.x;   // 2*512*64
    int j = idx >> 15, k = (idx >> 6) & 511, n = idx & 63;
    const float* wp = Wp + (size_t)k * DD;
    const float* wg = Wgm + (size_t)(j * NBLK + 0) * DD * DMM + n;
    float s = 0.f;
    for (int e = 0; e < DD; e++) s += wp[e] * wg[(size_t)e * DMM];
    wf[idx] = s;
  } else {
    int idx = (pb - 256) * 256 + threadIdx.x;
    if (idx >= NV * NBLK * DD * NH) return;
    int h = idx & 1, dd = (idx >> 1) & 127, lv = idx >> 8;
    const float* w = W_embed + dd * DD;
    const float* al = a_l + (lv * NH + h) * DD;
    const float* ar = a_r + (lv * NH + h) * DD;
    float sl = 0.f, sr = 0.f;
    for (int e = 0; e < DD; e++) { float we = w[e]; sl += we * al[e]; sr += we * ar[e]; }
    Bl[idx] = sl; Br[idx] = sr;
  }
}

// ---------------- fused: scan1 (blocks 0..59)  ||  wsplit hi-only (60..1307) ----------------
__global__ __launch_bounds__(256) void kB_scan1_wsplit(const int* __restrict__ deg, int* __restrict__ partial,
                                                       const float* __restrict__ Wp, const float* __restrict__ wf,
                                                       const float* __restrict__ Wv, const float* __restrict__ Wgm,
                                                       const float* __restrict__ Wt,
                                                       unsigned short* __restrict__ hi) {
  int b = blockIdx.x;
  if (b < 60) {
    int view = b / NCH, ch = b % NCH;
    const int* d = deg + view * NN + ch * CH;
    int rem = min(CH, NN - ch * CH);
    int t = threadIdx.x;
    int s = 0;
    for (int i = t; i < rem; i += 256) s += d[i];
    for (int k = 32; k; k >>= 1) s += __shfl_xor(s, k);
    __shared__ int wsum[4];
    if ((t & 63) == 0) wsum[t >> 6] = s;
    __syncthreads();
    if (t == 0) partial[b] = wsum[0] + wsum[1] + wsum[2] + wsum[3];
    return;
  }
  int wb = b - 60;
  const int pre[11] = {0, 256, 384, 512, 640, 768, 896, 1024, 1056, 1088, 1248};
  int y = 0;
  while (y < 10 && wb >= pre[y + 1]) y++;
  int bx = wb - pre[y];
  const float* src; int K, N; size_t doff;
  if (y == 0)      { src = Wp;                      K = 512; N = 128; doff = OFF_PROJVM; }
  else if (y <= 2) { int j = y - 1; src = wf + (size_t)j * 512 * 64; K = 512; N = 64; doff = OFF_PROJVM + (size_t)(128 + j * 64) * 512; }
  else if (y <= 6) { int lv = y - 3; src = Wv + (size_t)lv * 32768;  K = 256; N = 128; doff = OFF_WV + (size_t)lv * 32768; }
  else if (y <= 8) { int j = y - 7; src = Wgm + (size_t)(j * NBLK + 1) * 8192; K = 128; N = 64; doff = OFF_WGM + (size_t)j * 8192; }
  else             { src = Wt;                      K = 640; N = 64;  doff = OFF_TRAN; }
  int idx = bx * 256 + threadIdx.x;
  if (idx >= K * N) return;
  int n = idx / K, k = idx % K;
  int tk = k >> 6, g = (k >> 3) & 7, j2 = k & 7;
  int ks = (tk << 6) | ((g ^ (n & 7)) << 3) | j2;
  hi[doff + (size_t)n * K + ks] = f2bf(src[(size_t)k * N + n]);
}

// ---------------- scan3 with inlined scan2 ----------------
__global__ __launch_bounds__(256) void k_scan3(const int* __restrict__ deg, const int* __restrict__ partial,
                                               int* __restrict__ off) {
  int b = blockIdx.x, view = b / NCH, ch = b % NCH;
  int coff = 0;
  for (int c = 0; c < ch; c++) coff += partial[view * NCH + c];
  int base = ch * CH;
  const int* d = deg + view * NN;
  int* o = off + view * (NN + 1);
  int t = threadIdx.x, lane = t & 63, w = t >> 6;
  int i0 = base + t * 4;
  int x0 = 0, x1 = 0, x2 = 0, x3 = 0;
  if (i0 + 3 < NN) { int4 q = *(const int4*)(d + i0); x0 = q.x; x1 = q.y; x2 = q.z; x3 = q.w; }
  else {
    if (i0     < NN) x0 = d[i0];
    if (i0 + 1 < NN) x1 = d[i0 + 1];
    if (i0 + 2 < NN) x2 = d[i0 + 2];
  }
  int tot = x0 + x1 + x2 + x3;
  int incl = tot;
  for (int k = 1; k < 64; k <<= 1) { int y = __shfl_up(incl, k); if (lane >= k) incl += y; }
  __shared__ int wt[4];
  if (lane == 63) wt[w] = incl;
  __syncthreads();
  int wexcl = 0;
  for (int k = 0; k < w; k++) wexcl += wt[k];
  int excl = coff + wexcl + incl - tot;
  if (i0     < NN) o[i0]     = excl;
  if (i0 + 1 < NN) o[i0 + 1] = excl + x0;
  if (i0 + 2 < NN) o[i0 + 2] = excl + x0 + x1;
  if (i0 + 3 < NN) o[i0 + 3] = excl + x0 + x1 + x2;
  if (ch == NCH - 1 && t == 0) o[NN] = coff + partial[b];
}

// ---------------- edge aggregation + fused gate; 32-bit offset shuffles, 2-deep pipeline ----------------
__global__ __launch_bounds__(256) void k_edge(const int* __restrict__ off_, const int* __restrict__ csr_,
                                              const float4* __restrict__ lq_, const float2* __restrict__ lr_,
                                              const unsigned short* __restrict__ pk_, long viewStride,
                                              int ps, int vmoff0, int vmstep,
                                              const float* __restrict__ Wg_, const float* __restrict__ bg_,
                                              unsigned short* __restrict__ S_) {
  int view = blockIdx.y;
  const int* off = off_ + view * (NN + 1);
  const int* csr = csr_ + (size_t)view * EE;
  const float4* lq = lq_ + (size_t)view * NN;
  const float2* lrp = lr_ + (size_t)view * NN;
  const unsigned short* pk = pk_ + (size_t)view * viewStride;
  const char* pkc = (const char*)pk;
  int psb = ps * 2;
  int vmb = (vmoff0 + view * vmstep) * 2;
  const float* Wg = Wg_ + (size_t)view * NBLK * (2 * DD + DMM) * NH;
  const float* bg = bg_ + view * NBLK * NH;
  unsigned short* S = S_ + (size_t)view * NN * 256;

  int lane = threadIdx.x & 63, wid = threadIdx.x >> 6;
  int n = blockIdx.x * 4 + wid;
  int e0 = off[n], nb = off[n + 1] - e0;
  int half = lane >> 5, hl = lane & 31;
  if (nb == 0) {
    us4 z4 = {0, 0, 0, 0};
    *(us4*)(S + (size_t)n * 256 + half * 128 + 4 * hl) = z4;
    return;
  }
  float2 lrn = lrp[n];
  int voff = 8 * hl;
  int moff = vmb + 4 * hl;
  float sa0[4] = {0.f, 0.f, 0.f, 0.f}, sa1[4] = {0.f, 0.f, 0.f, 0.f};
  float d0 = 0.f, d1 = 0.f, tm0 = 0.f, tm1 = 0.f, vm0 = -INFINITY, vm1 = -INFINITY;
  for (int base = 0; base < nb; base += 64) {
    int i = base + lane;
    float w0 = 0.f, w1 = 0.f; unsigned boff = 0;
    if (i < nb) {
      int sidx = csr[e0 + i];
      boff = (unsigned)(sidx * psb);
      float4 qq = lq[sidx];
      float x0 = qq.x + lrn.x, x1 = qq.y + lrn.y;
      x0 = (x0 > 0.f) ? x0 : NEG_ATT * x0;
      x1 = (x1 > 0.f) ? x1 : NEG_ATT * x1;
      w0 = __expf(x0); w1 = __expf(x1);
      d0 += w0; d1 += w1; tm0 += qq.z; tm1 += qq.w;
    }
    int cnt = min(64, nb - base);
    int steps = (cnt + 1) >> 1;
    int j = half;
    unsigned bo = __shfl(boff, j);
    float wa = __shfl(w0, j), wb = __shfl(w1, j);
    us4 vq = *(const us4*)(pkc + bo + voff);
    unsigned mu = *(const unsigned*)(pkc + bo + moff);
    bool ok = (j < cnt);
    for (int s = 0; s < steps; s++) {
      int j1 = 2 * (s + 1) + half;
      int jc = min(j1, 63);
      unsigned bo1 = __shfl(boff, jc);
      float wa1 = __shfl(w0, jc), wb1 = __shfl(w1, jc);
      us4 vq1 = *(const us4*)(pkc + bo1 + voff);
      unsigned mu1 = *(const unsigned*)(pkc + bo1 + moff);
      float v0 = bf2f(vq[0]), v1 = bf2f(vq[1]), v2 = bf2f(vq[2]), v3 = bf2f(vq[3]);
      sa0[0] += wa * v0; sa0[1] += wa * v1; sa0[2] += wa * v2; sa0[3] += wa * v3;
      sa1[0] += wb * v0; sa1[1] += wb * v1; sa1[2] += wb * v2; sa1[3] += wb * v3;
      float mv0 = ok ? bf2f((unsigned short)mu) : -INFINITY;
      float mv1 = ok ? bf2f((unsigned short)(mu >> 16)) : -INFINITY;
      vm0 = fmaxf(vm0, mv0); vm1 = fmaxf(vm1, mv1);
      vq = vq1; mu = mu1; wa = wa1; wb = wb1; ok = (j1 < cnt);
    }
  }
#pragma unroll
  for (int k = 0; k < 4; k++) {
    sa0[k] += __shfl_xor(sa0[k], 32);
    sa1[k] += __shfl_xor(sa1[k], 32);
  }
  vm0 = fmaxf(vm0, __shfl_xor(vm0, 32));
  vm1 = fmaxf(vm1, __shfl_xor(vm1, 32));
  for (int s = 32; s; s >>= 1) { d0 += __shfl_xor(d0, s); d1 += __shfl_xor(d1, s); }
  unsigned vnu = *(const unsigned*)(pk + (size_t)n * ps + 2 * lane);
  float vnx = bf2f((unsigned short)vnu), vny = bf2f((unsigned short)(vnu >> 16));
  float im = 1.f / (float)nb;
  float p0 = vnx * Wg[(2 * lane) * 2]     + vny * Wg[(2 * lane + 1) * 2]     + tm0 * im;
  float p1 = vnx * Wg[(2 * lane) * 2 + 1] + vny * Wg[(2 * lane + 1) * 2 + 1] + tm1 * im;
  if (half == 1) {
    p0 += vm0 * Wg[(256 + 2 * hl) * 2]     + vm1 * Wg[(256 + 2 * hl + 1) * 2];
    p1 += vm0 * Wg[(256 + 2 * hl) * 2 + 1] + vm1 * Wg[(256 + 2 * hl + 1) * 2 + 1];
  }
  for (int s = 32; s; s >>= 1) { p0 += __shfl_xor(p0, s); p1 += __shfl_xor(p1, s); }
  float g0 = 1.f / (1.f + __expf(-(p0 + bg[0])));
  float g1 = 1.f / (1.f + __expf(-(p1 + bg[1])));
  float q0 = g0 / d0, q1 = g1 / d1;
  us4 o4;
  if (half == 0) {
    o4[0] = f2bf(sa0[0] * q0); o4[1] = f2bf(sa0[1] * q0);
    o4[2] = f2bf(sa0[2] * q0); o4[3] = f2bf(sa0[3] * q0);
  } else {
    o4[0] = f2bf(sa1[0] * q1); o4[1] = f2bf(sa1[1] * q1);
    o4[2] = f2bf(sa1[2] * q1); o4[3] = f2bf(sa1[3] * q1);
  }
  *(us4*)(S + (size_t)n * 256 + half * 128 + 4 * hl) = o4;
}

// ---------------- pure-bf16 MFMA GEMM + fused fill prefix + fused llr epilogue ----------------
// flags: bit1 = leaky_relu; bit3 = first 938 x-blocks/z do edge-fill.
// EPI: 0 = none; 1 = proj (z==0 blocks compute BOTH views' layer-0 logits);
//      2 = mean-merge (each z-block computes its view's layer-1 logits).
struct GB {
  const void* A[4];
  unsigned long long bofs[4];
  float* C[4];
  unsigned short* P[4];
  unsigned short* P2[4];
  int ldc[4];
  int pldc[4];
  int p2ldc[4];
};

template <int BN, int BM, bool ABF, int EPI>
__global__ __launch_bounds__(256) void gemm_mfma(
    GB gb, AUX aux, const unsigned short* __restrict__ Bth,
    int lda, int ldb, int M, int K,
    const float* __restrict__ bias, float fs, int flags) {
  constexpr int NSUB = BN / 32;
  constexpr int CPW = BN / 32;
  constexpr int MS = BM / 32;
  __shared__ __align__(16) unsigned short SMEM[BM * 64 + BN * 64];
  int xb = blockIdx.x;
  const int z = blockIdx.z;
  if (flags & 8) {
    if (xb < 938) { fill_body(xb + 938 * z, threadIdx.x, aux); return; }
    xb -= 938;
  }
  const float* __restrict__ Af = (const float*)gb.A[z];
  const unsigned short* __restrict__ Ab = (const unsigned short*)gb.A[z];
  float* __restrict__ C = gb.C[z];
  unsigned short* __restrict__ P = gb.P[z];
  unsigned short* __restrict__ P2 = gb.P2[z];
  const int ldc = gb.ldc[z], pldc = gb.pldc[z], p2ldc = gb.p2ldc[z];
  const size_t bofs = gb.bofs[z];
  const int t = threadIdx.x;
  const int lane = t & 63, wv = t >> 6;
  const int lm = lane & 15, lg = lane >> 4;
  const int m0w = (wv & 1) * (BM / 2), n0w = (wv >> 1) * (BN / 2);
  const int row0 = xb * BM;
  f32x4 acc[MS][NSUB];
#pragma unroll
  for (int ms = 0; ms < MS; ms++)
#pragma unroll
    for (int ns = 0; ns < NSUB; ns++) acc[ms][ns] = (f32x4)0.f;

  float4 apre[MS][2];
  const int ar_ = t >> 3, ag_ = t & 7;

  auto loadA = [&](int k0) {
    if constexpr (!ABF) {
#pragma unroll
      for (int q = 0; q < MS; q++) {
        int rr = row0 + q * 32 + ar_;
        if (rr < M) {
          const float* p = Af + (size_t)rr * lda + k0 + ag_ * 8;
          apre[q][0] = *(const float4*)p;
          apre[q][1] = *(const float4*)(p + 4);
        } else {
          apre[q][0] = make_float4(0.f, 0.f, 0.f, 0.f);
          apre[q][1] = make_float4(0.f, 0.f, 0.f, 0.f);
        }
      }
    }
  };
  auto storeA = [&]() {
    if constexpr (!ABF) {
#pragma unroll
      for (int q = 0; q < MS; q++) {
        int r = q * 32 + ar_;
        us8 h8;
        float vals[8] = {apre[q][0].x, apre[q][0].y, apre[q][0].z, apre[q][0].w,
                         apre[q][1].x, apre[q][1].y, apre[q][1].z, apre[q][1].w};
#pragma unroll
        for (int e = 0; e < 8; e++) h8[e] = f2bf(vals[e]);
        int c = (ag_ ^ (r & 7)) << 3;
        *(us8*)&SMEM[r * 64 + c] = h8;
      }
    }
  };
  auto stageA_bf = [&](int k0) {
    if constexpr (ABF) {
#pragma unroll
      for (int q = 0; q < MS; q++) {
        int r = q * 32 + ar_;
        int rr = min(row0 + r, M - 1);
        int scg = ag_ ^ (r & 7);
        gload16((char*)&SMEM[0] + q * 4096 + t * 16,
                Ab + (size_t)rr * lda + k0 + scg * 8);
      }
    }
  };
  auto stageB = [&](int k0) {
#pragma unroll
    for (int q = 0; q < CPW; q++) {
      int chunk = wv * CPW + q;
      int o = chunk * 1024 + lane * 16;
      int n = o >> 7;
      int pq = (o >> 4) & 7;
      size_t gofs = bofs + (size_t)n * ldb + k0 + pq * 8;
      gload16((char*)&SMEM[BM * 64] + o, Bth + gofs);
    }
  };

  loadA(0);
  for (int k0 = 0; k0 < K; k0 += 64) {
    if constexpr (ABF) stageA_bf(k0); else storeA();
    stageB(k0);
    __syncthreads();
    if constexpr (!ABF) { if (k0 + 64 < K) loadA(k0 + 64); }
#pragma unroll
    for (int kc = 0; kc < 2; kc++) {
      bf16x8 afh[MS], bfh[NSUB];
#pragma unroll
      for (int ms = 0; ms < MS; ms++) {
        int R = m0w + ms * 16 + lm;
        int c = (((kc * 4 + lg) ^ (R & 7)) << 3);
        afh[ms] = *(const bf16x8*)&SMEM[R * 64 + c];
      }
#pragma unroll
      for (int ns = 0; ns < NSUB; ns++) {
        int R = n0w + ns * 16 + lm;
        int c = (((kc * 4 + lg) ^ (R & 7)) << 3);
        bfh[ns] = *(const bf16x8*)&SMEM[BM * 64 + R * 64 + c];
      }
#pragma unroll
      for (int ms = 0; ms < MS; ms++)
#pragma unroll
        for (int ns = 0; ns < NSUB; ns++)
          acc[ms][ns] = __builtin_amdgcn_mfma_f32_16x16x32_bf16(afh[ms], bfh[ns], acc[ms][ns], 0, 0, 0);
    }
    __syncthreads();
  }
  // epilogue: global writes (+ tile store for llr epilogue)
#pragma unroll
  for (int ms = 0; ms < MS; ms++)
#pragma unroll
    for (int ns = 0; ns < NSUB; ns++)
#pragma unroll
      for (int j = 0; j < 4; j++) {
        int r = m0w + ms * 16 + lg * 4 + j;
        int row = row0 + r;
        int col = n0w + ns * 16 + lm;
        float val = acc[ms][ns][j] * fs;
        if (bias) val += bias[col];
        if (flags & 2) val = (val > 0.f) ? val : NEG_OUT * val;
        unsigned short bv = f2bf(val);
        if constexpr (EPI != 0) {
          int p = col >> 6, cc = col & 63, g = cc >> 3, jj = cc & 7;
          SMEM[p * (BM * 64) + r * 64 + (((g ^ (r & 7)) << 3) | jj)] = bv;
        }
        if (row < M) {
          if (C) C[(size_t)row * ldc + col] = val;
          if (P) P[(size_t)row * pldc + col] = bv;
          if (P2) P2[(size_t)row * p2ldc + col] = bv;
        }
      }
  if constexpr (EPI != 0) {
    if (EPI == 2 || z == 0) {
      __syncthreads();
      const float* vBl = (EPI == 2 && z) ? aux.lBl1 : aux.lBl0;
      const float* vBr = (EPI == 2 && z) ? aux.lBr1 : aux.lBr0;
      const float* vWg = (EPI == 2 && z) ? aux.lWg1 : aux.lWg0;
      float4 cb0 = *(const float4*)(vBl + 4 * lane);
      float4 cr0 = *(const float4*)(vBr + 4 * lane);
      float4 cg0 = *(const float4*)(vWg + 256 + 4 * lane);
      float4 cb1, cr1, cg1;
      if constexpr (EPI == 1) {
        cb1 = *(const float4*)(aux.lBl1 + 4 * lane);
        cr1 = *(const float4*)(aux.lBr1 + 4 * lane);
        cg1 = *(const float4*)(aux.lWg1 + 256 + 4 * lane);
      }
      int pp = lane >> 5, cc = (2 * lane) & 63, gg = cc >> 3, jj2 = cc & 7;
      for (int i = 0; i < BM / 4; i++) {
        int r = wv * (BM / 4) + i;
        int n = row0 + r;
        unsigned u = *(const unsigned*)&SMEM[pp * (BM * 64) + r * 64 + (((gg ^ (r & 7)) << 3) | jj2)];
        float ax = bf2f((unsigned short)u), ay = bf2f((unsigned short)(u >> 16));
        float rv[12];
        rv[0] = ax * cb0.x + ay * cb0.z;  rv[1] = ax * cb0.y + ay * cb0.w;
        rv[2] = ax * cr0.x + ay * cr0.z;  rv[3] = ax * cr0.y + ay * cr0.w;
        rv[4] = ax * cg0.x + ay * cg0.z;  rv[5] = ax * cg0.y + ay * cg0.w;
        if constexpr (EPI == 1) {
          rv[6]  = ax * cb1.x + ay * cb1.z;  rv[7]  = ax * cb1.y + ay * cb1.w;
          rv[8]  = ax * cr1.x + ay * cr1.z;  rv[9]  = ax * cr1.y + ay * cr1.w;
          rv[10] = ax * cg1.x + ay * cg1.z;  rv[11] = ax * cg1.y + ay * cg1.w;
        }
        constexpr int NR = (EPI == 1) ? 12 : 6;
        for (int s = 32; s; s >>= 1)
#pragma unroll
          for (int q = 0; q < NR; q++) rv[q] += __shfl_xor(rv[q], s);
        if (lane == 0 && n < NN) {
          if constexpr (EPI == 1) {
            aux.llq[n] = make_float4(rv[0], rv[1], rv[4], rv[5]);
            aux.llr[n] = make_float2(rv[2], rv[3]);
            aux.llq[NN + n] = make_float4(rv[6], rv[7], rv[10], rv[11]);
            aux.llr[NN + n] = make_float2(rv[8], rv[9]);
          } else {
            aux.llq[(size_t)z * NN + n] = make_float4(rv[0], rv[1], rv[4], rv[5]);
            aux.llr[(size_t)z * NN + n] = make_float2(rv[2], rv[3]);
          }
        }
      }
    }
  }
}

extern "C" void kernel_launch(void* const* d_in, const int* in_sizes, int n_in,
                              void* d_out, int out_size, void* d_ws, size_t ws_size,
                              hipStream_t stream) {
  const float* ft      = (const float*)d_in[0];
  const int*   src     = (const int*)  d_in[1];
  const int*   dst     = (const int*)  d_in[2];
  const float* W_proj  = (const float*)d_in[3];
  const float* W_embed = (const float*)d_in[4];
  const float* a_l     = (const float*)d_in[5];
  const float* a_r     = (const float*)d_in[6];
  const float* Wv      = (const float*)d_in[7];
  const float* Wgm     = (const float*)d_in[8];
  const float* Wgate   = (const float*)d_in[9];
  const float* b_gate  = (const float*)d_in[10];
  const float* W_tran  = (const float*)d_in[11];
  const float* b_tran  = (const float*)d_in[12];
  float* out = (float*)d_out;
  char* ws = (char*)d_ws;
  (void)in_sizes; (void)n_in; (void)out_size; (void)ws_size;

  size_t o = 0;
  auto take = [&](size_t bytes) { size_t r = o; o += (bytes + 255) & ~(size_t)255; return r; };
  int*   deg     = (int*)(ws + take((size_t)NV * NN * 4));
  int*   cursor  = (int*)(ws + take((size_t)NV * NN * 4));
  int*   csr_off = (int*)(ws + take((size_t)NV * (NN + 1) * 4));
  int*   csr_src = (int*)(ws + take((size_t)NV * EE * 4));
  int*   partial = (int*)(ws + take((size_t)NV * NCH * 4));
  float* Bl      = (float*)(ws + take((size_t)NV * NBLK * DD * NH * 4));
  float* Br      = (float*)(ws + take((size_t)NV * NBLK * DD * NH * 4));
  float* wf      = (float*)(ws + take((size_t)NV * 512 * 64 * 4));
  unsigned short* whi = (unsigned short*)(ws + take((size_t)WT_TOTAL * 2));
  unsigned short* hb  = (unsigned short*)(ws + take((size_t)NN * 640 * 2));  // [N,640] bf16
  unsigned short* pk0 = (unsigned short*)(ws + take((size_t)NN * 256 * 2));
  unsigned short* pk1 = (unsigned short*)(ws + take((size_t)NV * NN * 192 * 2));
  unsigned short* Sbf = (unsigned short*)(ws + take((size_t)NV * NN * 256 * 2));
  float4* lqb    = (float4*)(ws + take((size_t)NV * NN * 16));
  float2* lrb    = (float2*)(ws + take((size_t)NV * NN * 8));

  const int GMB = (NN + 127) / 128;  // 235

  hipMemsetAsync(deg, 0, (size_t)(((size_t)NV * NN * 4 + 255) & ~(size_t)255) + (size_t)NV * NN * 4, stream);
  kA_deg_prepw<<<2135, 256, 0, stream>>>(dst, deg, W_embed, a_l, a_r, W_proj, Wgm, Bl, Br, wf);
  kB_scan1_wsplit<<<1308, 256, 0, stream>>>(deg, partial, W_proj, wf, Wv, Wgm, W_tran, whi);
  k_scan3<<<NV * NCH, 256, 0, stream>>>(deg, partial, csr_off);

  // [fill ∥ proj GEMM + llr0 epilogue]
  {
    GB gb = {};
    gb.A[0] = ft; gb.A[1] = ft;
    gb.bofs[0] = OFF_PROJVM; gb.bofs[1] = OFF_PROJVM + (size_t)128 * 512;
    gb.P[0] = pk0;        gb.pldc[0] = 256;
    gb.P2[0] = hb;        gb.p2ldc[0] = 640;
    gb.P[1] = pk0 + 128;  gb.pldc[1] = 256;
    AUX ax = {};
    ax.fsrc = src; ax.fdst = dst; ax.foff = csr_off; ax.fcur = cursor; ax.fcsr = csr_src;
    ax.lBl0 = Bl + 0 * 256; ax.lBr0 = Br + 0 * 256; ax.lWg0 = Wgate;
    ax.lBl1 = Bl + 2 * 256; ax.lBr1 = Br + 2 * 256; ax.lWg1 = Wgate + (size_t)NBLK * 320 * NH;
    ax.llq = lqb; ax.llr = lrb;
    gemm_mfma<128, 128, false, 1><<<dim3(938 + GMB, 1, 2), 256, 0, stream>>>(gb, ax, whi, IN_DIM, 512,
                                                                             NN, 512, nullptr, 1.f, 8);
  }
  k_edge<<<dim3(NN / 4, 2), 256, 0, stream>>>(csr_off, csr_src, lqb, lrb,
                                              pk0, 0L, 256, 128, 64,
                                              Wgate, b_gate, Sbf);
  // mean merge -> pk1 v-part + llr1 epilogue
  {
    GB gb = {};
    for (int j = 0; j < 2; j++) {
      gb.A[j] = Sbf + (size_t)j * NN * 256;
      gb.bofs[j] = OFF_WV + (size_t)(j * 2) * 32768;
      gb.P[j] = pk1 + (size_t)j * NN * 192;
      gb.pldc[j] = 192;
    }
    AUX ax = {};
    ax.lBl0 = Bl + 1 * 256; ax.lBr0 = Br + 1 * 256; ax.lWg0 = Wgate + 640;
    ax.lBl1 = Bl + 3 * 256; ax.lBr1 = Br + 3 * 256; ax.lWg1 = Wgate + (size_t)NBLK * 640 + 640;
    ax.llq = lqb; ax.llr = lrb;
    gemm_mfma<128, 128, true, 2><<<dim3(GMB, 1, 2), 256, 0, stream>>>(gb, ax, whi, 256, 256, NN, 256,
                                                                      nullptr, 0.5f, 2);
  }
  // vm = l0 @ Wgm[:,1] -> pk1 vm-part
  {
    GB gb = {};
    for (int j = 0; j < 2; j++) {
      gb.A[j] = pk1 + (size_t)j * NN * 192;
      gb.bofs[j] = OFF_WGM + (size_t)j * 8192;
      gb.P[j] = pk1 + (size_t)j * NN * 192 + 128;
      gb.pldc[j] = 192;
    }
    AUX ax = {};
    gemm_mfma<64, 128, true, 0><<<dim3(GMB, 1, 2), 256, 0, stream>>>(gb, ax, whi, 192, 128,
                                                                     NN, 128, nullptr, 1.f, 0);
  }
  k_edge<<<dim3(NN / 4, 2), 256, 0, stream>>>(csr_off, csr_src, lqb, lrb,
                                              pk1, (long)NN * 192, 192, 128, 0,
                                              Wgate + 640, b_gate + NH, Sbf);
  // cat merge -> hb[:,128..640] bf16, per (view, head), K=128
  {
    GB gb = {};
    for (int z = 0; z < 4; z++) {
      int j = z >> 1, hd = z & 1;
      gb.A[z] = Sbf + (size_t)j * NN * 256 + hd * 128;
      gb.bofs[z] = OFF_WV + (size_t)(j * 2 + 1) * 32768 + hd * 128;
      gb.P[z] = hb + 128 + z * 128;
      gb.pldc[z] = 640;
    }
    AUX ax = {};
    gemm_mfma<128, 128, true, 0><<<dim3(GMB, 1, 4), 256, 0, stream>>>(gb, ax, whi, 256, 256, NN, 128,
                                                                      nullptr, 1.f, 2);
  }
  // out = hb @ W_tran + b_tran  (bf16 A)
  {
    GB gb = {};
    gb.A[0] = hb; gb.bofs[0] = OFF_TRAN; gb.C[0] = out; gb.ldc[0] = OUTD;
    AUX ax = {};
    gemm_mfma<64, 128, true, 0><<<dim3(GMB, 1, 1), 256, 0, stream>>>(gb, ax, whi, 640, 640, NN, 640,
                                                                     b_tran, 1.f, 0);
  }
}

// Round 16
// 295.190 us; speedup vs baseline: 1.1530x; 1.1530x over previous
//
#include <hip/hip_runtime.h>
#include <hip/hip_bf16.h>
#include <math.h>

#define NN 30000
#define EE 240000
#define IN_DIM 512
#define DD 128
#define OUTD 64
#define NV 2
#define NBLK 2
#define NH 2
#define DMM 64
#define NEG_ATT 0.2f
#define NEG_OUT 0.01f
#define CH 1024
#define NCH ((NN + CH - 1) / CH)   // 30

typedef __attribute__((ext_vector_type(8))) short bf16x8;
typedef __attribute__((ext_vector_type(4))) float f32x4;
typedef __attribute__((ext_vector_type(4))) unsigned short us4;
typedef __attribute__((ext_vector_type(8))) unsigned short us8;

// weight-plane offsets (hwords)
#define OFF_PROJVM 0
#define OFF_WV     131072
#define OFF_WGM    262144
#define OFF_TRAN   278528
#define WT_TOTAL   319488

__device__ __forceinline__ unsigned short f2bf(float x) {
  unsigned u = __float_as_uint(x);
  return (unsigned short)((u + 0x7FFFu + ((u >> 16) & 1u)) >> 16);
}
__device__ __forceinline__ float bf2f(unsigned short u) {
  return __uint_as_float((unsigned)u << 16);
}
__device__ __forceinline__ void gload16(void* lds, const void* g) {
  __builtin_amdgcn_global_load_lds((const __attribute__((address_space(1))) unsigned int*)g,
                                   (__attribute__((address_space(3))) unsigned int*)lds, 16, 0, 0);
}

// auxiliary work descriptors for fused launches
struct AUX {
  const int* fsrc; const int* fdst; const int* foff; int* fcur; int* fcsr;   // edge fill
  const unsigned short* lp0; const unsigned short* lp1; int lps;             // llr
  const float *lBl0, *lBr0, *lBl1, *lBr1, *lWg0, *lWg1;
  float4* llq; float2* llr;
};

__device__ void fill_body(int fb, int t, const AUX& a) {
  int e = fb * 256 + t;
  if (e >= NV * EE) return;
  int view = e / EE;
  int d = a.fdst[e];
  int p = atomicAdd(&a.fcur[view * NN + d], 1);
  a.fcsr[view * EE + a.foff[view * (NN + 1) + d] + p] = a.fsrc[e];
}

__device__ void llr_body(int lid, int t, const AUX& a) {
  int lane = t & 63, wid = t >> 6;
  int n = lid * 4 + wid;
  if (n >= NN) return;
  int k = lane * 2;
  unsigned av = *(const unsigned*)(a.lp0 + (size_t)n * a.lps + k);
  unsigned bv = *(const unsigned*)(a.lp1 + (size_t)n * a.lps + k);
  float ax = bf2f((unsigned short)av), ay = bf2f((unsigned short)(av >> 16));
  float bx = bf2f((unsigned short)bv), by = bf2f((unsigned short)(bv >> 16));
  float r[12];
  r[0]  = ax * a.lBl0[k * 2]     + ay * a.lBl0[k * 2 + 2];
  r[1]  = ax * a.lBl0[k * 2 + 1] + ay * a.lBl0[k * 2 + 3];
  r[2]  = ax * a.lBr0[k * 2]     + ay * a.lBr0[k * 2 + 2];
  r[3]  = ax * a.lBr0[k * 2 + 1] + ay * a.lBr0[k * 2 + 3];
  r[4]  = ax * a.lWg0[(128 + k) * 2]     + ay * a.lWg0[(129 + k) * 2];
  r[5]  = ax * a.lWg0[(128 + k) * 2 + 1] + ay * a.lWg0[(129 + k) * 2 + 1];
  r[6]  = bx * a.lBl1[k * 2]     + by * a.lBl1[k * 2 + 2];
  r[7]  = bx * a.lBl1[k * 2 + 1] + by * a.lBl1[k * 2 + 3];
  r[8]  = bx * a.lBr1[k * 2]     + by * a.lBr1[k * 2 + 2];
  r[9]  = bx * a.lBr1[k * 2 + 1] + by * a.lBr1[k * 2 + 3];
  r[10] = bx * a.lWg1[(128 + k) * 2]     + by * a.lWg1[(129 + k) * 2];
  r[11] = bx * a.lWg1[(128 + k) * 2 + 1] + by * a.lWg1[(129 + k) * 2 + 1];
  for (int s = 32; s; s >>= 1)
#pragma unroll
    for (int q = 0; q < 12; q++) r[q] += __shfl_xor(r[q], s);
  if (lane == 0) {
    a.llq[n] = make_float4(r[0], r[1], r[4], r[5]);
    a.llr[n] = make_float2(r[2], r[3]);
    a.llq[NN + n] = make_float4(r[6], r[7], r[10], r[11]);
    a.llr[NN + n] = make_float2(r[8], r[9]);
  }
}

// ---------------- fused: deg histogram (blocks 0..1874)  ||  prepw (1875..2134) ----------------
__global__ __launch_bounds__(256) void kA_deg_prepw(const int* __restrict__ dst, int* __restrict__ deg,
                                                    const float* __restrict__ W_embed,
                                                    const float* __restrict__ a_l, const float* __restrict__ a_r,
                                                    const float* __restrict__ Wp, const float* __restrict__ Wgm,
                                                    float* __restrict__ Bl, float* __restrict__ Br,
                                                    float* __restrict__ wf) {
  int b = blockIdx.x;
  if (b < 1875) {
    int e = b * 256 + threadIdx.x;
    if (e < NV * EE) atomicAdd(&deg[(e / EE) * NN + dst[e]], 1);
    return;
  }
  int pb = b - 1875;
  if (pb < 256) {
    int idx = pb * 256 + threadIdx.x;   // 2*512*64
    int j = idx >> 15, k = (idx >> 6) & 511, n = idx & 63;
    const float* wp = Wp + (size_t)k * DD;
    const float* wg = Wgm + (size_t)(j * NBLK + 0) * DD * DMM + n;
    float s = 0.f;
    for (int e = 0; e < DD; e++) s += wp[e] * wg[(size_t)e * DMM];
    wf[idx] = s;
  } else {
    int idx = (pb - 256) * 256 + threadIdx.x;
    if (idx >= NV * NBLK * DD * NH) return;
    int h = idx & 1, dd = (idx >> 1) & 127, lv = idx >> 8;
    const float* w = W_embed + dd * DD;
    const float* al = a_l + (lv * NH + h) * DD;
    const float* ar = a_r + (lv * NH + h) * DD;
    float sl = 0.f, sr = 0.f;
    for (int e = 0; e < DD; e++) { float we = w[e]; sl += we * al[e]; sr += we * ar[e]; }
    Bl[idx] = sl; Br[idx] = sr;
  }
}

// ---------------- fused: scan1 (blocks 0..59)  ||  wsplit hi-only (60..1307) ----------------
__global__ __launch_bounds__(256) void kB_scan1_wsplit(const int* __restrict__ deg, int* __restrict__ partial,
                                                       const float* __restrict__ Wp, const float* __restrict__ wf,
                                                       const float* __restrict__ Wv, const float* __restrict__ Wgm,
                                                       const float* __restrict__ Wt,
                                                       unsigned short* __restrict__ hi) {
  int b = blockIdx.x;
  if (b < 60) {
    int view = b / NCH, ch = b % NCH;
    const int* d = deg + view * NN + ch * CH;
    int rem = min(CH, NN - ch * CH);
    int t = threadIdx.x;
    int s = 0;
    for (int i = t; i < rem; i += 256) s += d[i];
    for (int k = 32; k; k >>= 1) s += __shfl_xor(s, k);
    __shared__ int wsum[4];
    if ((t & 63) == 0) wsum[t >> 6] = s;
    __syncthreads();
    if (t == 0) partial[b] = wsum[0] + wsum[1] + wsum[2] + wsum[3];
    return;
  }
  int wb = b - 60;
  const int pre[11] = {0, 256, 384, 512, 640, 768, 896, 1024, 1056, 1088, 1248};
  int y = 0;
  while (y < 10 && wb >= pre[y + 1]) y++;
  int bx = wb - pre[y];
  const float* src; int K, N; size_t doff;
  if (y == 0)      { src = Wp;                      K = 512; N = 128; doff = OFF_PROJVM; }
  else if (y <= 2) { int j = y - 1; src = wf + (size_t)j * 512 * 64; K = 512; N = 64; doff = OFF_PROJVM + (size_t)(128 + j * 64) * 512; }
  else if (y <= 6) { int lv = y - 3; src = Wv + (size_t)lv * 32768;  K = 256; N = 128; doff = OFF_WV + (size_t)lv * 32768; }
  else if (y <= 8) { int j = y - 7; src = Wgm + (size_t)(j * NBLK + 1) * 8192; K = 128; N = 64; doff = OFF_WGM + (size_t)j * 8192; }
  else             { src = Wt;                      K = 640; N = 64;  doff = OFF_TRAN; }
  int idx = bx * 256 + threadIdx.x;
  if (idx >= K * N) return;
  int n = idx / K, k = idx % K;
  int tk = k >> 6, g = (k >> 3) & 7, j2 = k & 7;
  int ks = (tk << 6) | ((g ^ (n & 7)) << 3) | j2;
  hi[doff + (size_t)n * K + ks] = f2bf(src[(size_t)k * N + n]);
}

// ---------------- scan3 with inlined scan2 ----------------
__global__ __launch_bounds__(256) void k_scan3(const int* __restrict__ deg, const int* __restrict__ partial,
                                               int* __restrict__ off) {
  int b = blockIdx.x, view = b / NCH, ch = b % NCH;
  int coff = 0;
  for (int c = 0; c < ch; c++) coff += partial[view * NCH + c];
  int base = ch * CH;
  const int* d = deg + view * NN;
  int* o = off + view * (NN + 1);
  int t = threadIdx.x, lane = t & 63, w = t >> 6;
  int i0 = base + t * 4;
  int x0 = 0, x1 = 0, x2 = 0, x3 = 0;
  if (i0 + 3 < NN) { int4 q = *(const int4*)(d + i0); x0 = q.x; x1 = q.y; x2 = q.z; x3 = q.w; }
  else {
    if (i0     < NN) x0 = d[i0];
    if (i0 + 1 < NN) x1 = d[i0 + 1];
    if (i0 + 2 < NN) x2 = d[i0 + 2];
  }
  int tot = x0 + x1 + x2 + x3;
  int incl = tot;
  for (int k = 1; k < 64; k <<= 1) { int y = __shfl_up(incl, k); if (lane >= k) incl += y; }
  __shared__ int wt[4];
  if (lane == 63) wt[w] = incl;
  __syncthreads();
  int wexcl = 0;
  for (int k = 0; k < w; k++) wexcl += wt[k];
  int excl = coff + wexcl + incl - tot;
  if (i0     < NN) o[i0]     = excl;
  if (i0 + 1 < NN) o[i0 + 1] = excl + x0;
  if (i0 + 2 < NN) o[i0 + 2] = excl + x0 + x1;
  if (i0 + 3 < NN) o[i0 + 3] = excl + x0 + x1 + x2;
  if (ch == NCH - 1 && t == 0) o[NN] = coff + partial[b];
}

// ---------------- standalone k_llr (layer 0) ----------------
__global__ __launch_bounds__(256) void k_llr(AUX a) {
  llr_body(blockIdx.x, threadIdx.x, a);
}

// ---------------- edge aggregation + fused gate; 32-bit offset shuffles, 2-deep pipeline ----------------
__global__ __launch_bounds__(256) void k_edge(const int* __restrict__ off_, const int* __restrict__ csr_,
                                              const float4* __restrict__ lq_, const float2* __restrict__ lr_,
                                              const unsigned short* __restrict__ pk_, long viewStride,
                                              int ps, int vmoff0, int vmstep,
                                              const float* __restrict__ Wg_, const float* __restrict__ bg_,
                                              unsigned short* __restrict__ S_) {
  int view = blockIdx.y;
  const int* off = off_ + view * (NN + 1);
  const int* csr = csr_ + (size_t)view * EE;
  const float4* lq = lq_ + (size_t)view * NN;
  const float2* lrp = lr_ + (size_t)view * NN;
  const unsigned short* pk = pk_ + (size_t)view * viewStride;
  const char* pkc = (const char*)pk;
  int psb = ps * 2;
  int vmb = (vmoff0 + view * vmstep) * 2;
  const float* Wg = Wg_ + (size_t)view * NBLK * (2 * DD + DMM) * NH;
  const float* bg = bg_ + view * NBLK * NH;
  unsigned short* S = S_ + (size_t)view * NN * 256;

  int lane = threadIdx.x & 63, wid = threadIdx.x >> 6;
  int n = blockIdx.x * 4 + wid;
  int e0 = off[n], nb = off[n + 1] - e0;
  int half = lane >> 5, hl = lane & 31;
  if (nb == 0) {
    us4 z4 = {0, 0, 0, 0};
    *(us4*)(S + (size_t)n * 256 + half * 128 + 4 * hl) = z4;
    return;
  }
  float2 lrn = lrp[n];
  int voff = 8 * hl;
  int moff = vmb + 4 * hl;
  float sa0[4] = {0.f, 0.f, 0.f, 0.f}, sa1[4] = {0.f, 0.f, 0.f, 0.f};
  float d0 = 0.f, d1 = 0.f, tm0 = 0.f, tm1 = 0.f, vm0 = -INFINITY, vm1 = -INFINITY;
  for (int base = 0; base < nb; base += 64) {
    int i = base + lane;
    float w0 = 0.f, w1 = 0.f; unsigned boff = 0;
    if (i < nb) {
      int sidx = csr[e0 + i];
      boff = (unsigned)(sidx * psb);
      float4 qq = lq[sidx];
      float x0 = qq.x + lrn.x, x1 = qq.y + lrn.y;
      x0 = (x0 > 0.f) ? x0 : NEG_ATT * x0;
      x1 = (x1 > 0.f) ? x1 : NEG_ATT * x1;
      w0 = __expf(x0); w1 = __expf(x1);
      d0 += w0; d1 += w1; tm0 += qq.z; tm1 += qq.w;
    }
    int cnt = min(64, nb - base);
    int steps = (cnt + 1) >> 1;
    int j = half;
    unsigned bo = __shfl(boff, j);
    float wa = __shfl(w0, j), wb = __shfl(w1, j);
    us4 vq = *(const us4*)(pkc + bo + voff);
    unsigned mu = *(const unsigned*)(pkc + bo + moff);
    bool ok = (j < cnt);
    for (int s = 0; s < steps; s++) {
      int j1 = 2 * (s + 1) + half;
      int jc = min(j1, 63);
      unsigned bo1 = __shfl(boff, jc);
      float wa1 = __shfl(w0, jc), wb1 = __shfl(w1, jc);
      us4 vq1 = *(const us4*)(pkc + bo1 + voff);
      unsigned mu1 = *(const unsigned*)(pkc + bo1 + moff);
      float v0 = bf2f(vq[0]), v1 = bf2f(vq[1]), v2 = bf2f(vq[2]), v3 = bf2f(vq[3]);
      sa0[0] += wa * v0; sa0[1] += wa * v1; sa0[2] += wa * v2; sa0[3] += wa * v3;
      sa1[0] += wb * v0; sa1[1] += wb * v1; sa1[2] += wb * v2; sa1[3] += wb * v3;
      float mv0 = ok ? bf2f((unsigned short)mu) : -INFINITY;
      float mv1 = ok ? bf2f((unsigned short)(mu >> 16)) : -INFINITY;
      vm0 = fmaxf(vm0, mv0); vm1 = fmaxf(vm1, mv1);
      vq = vq1; mu = mu1; wa = wa1; wb = wb1; ok = (j1 < cnt);
    }
  }
#pragma unroll
  for (int k = 0; k < 4; k++) {
    sa0[k] += __shfl_xor(sa0[k], 32);
    sa1[k] += __shfl_xor(sa1[k], 32);
  }
  vm0 = fmaxf(vm0, __shfl_xor(vm0, 32));
  vm1 = fmaxf(vm1, __shfl_xor(vm1, 32));
  for (int s = 32; s; s >>= 1) { d0 += __shfl_xor(d0, s); d1 += __shfl_xor(d1, s); }
  unsigned vnu = *(const unsigned*)(pk + (size_t)n * ps + 2 * lane);
  float vnx = bf2f((unsigned short)vnu), vny = bf2f((unsigned short)(vnu >> 16));
  float im = 1.f / (float)nb;
  float p0 = vnx * Wg[(2 * lane) * 2]     + vny * Wg[(2 * lane + 1) * 2]     + tm0 * im;
  float p1 = vnx * Wg[(2 * lane) * 2 + 1] + vny * Wg[(2 * lane + 1) * 2 + 1] + tm1 * im;
  if (half == 1) {
    p0 += vm0 * Wg[(256 + 2 * hl) * 2]     + vm1 * Wg[(256 + 2 * hl + 1) * 2];
    p1 += vm0 * Wg[(256 + 2 * hl) * 2 + 1] + vm1 * Wg[(256 + 2 * hl + 1) * 2 + 1];
  }
  for (int s = 32; s; s >>= 1) { p0 += __shfl_xor(p0, s); p1 += __shfl_xor(p1, s); }
  float g0 = 1.f / (1.f + __expf(-(p0 + bg[0])));
  float g1 = 1.f / (1.f + __expf(-(p1 + bg[1])));
  float q0 = g0 / d0, q1 = g1 / d1;
  us4 o4;
  if (half == 0) {
    o4[0] = f2bf(sa0[0] * q0); o4[1] = f2bf(sa0[1] * q0);
    o4[2] = f2bf(sa0[2] * q0); o4[3] = f2bf(sa0[3] * q0);
  } else {
    o4[0] = f2bf(sa1[0] * q1); o4[1] = f2bf(sa1[1] * q1);
    o4[2] = f2bf(sa1[2] * q1); o4[3] = f2bf(sa1[3] * q1);
  }
  *(us4*)(S + (size_t)n * 256 + half * 128 + 4 * hl) = o4;
}

// ---------------- pure-bf16 MFMA GEMM, BM-parameterized, fused aux blocks ----------------
// flags: bit1 = leaky_relu; bit3 = first 938 x-blocks/z do edge-fill; bit4 = first 3750 x-blocks/z do llr.
struct GB {
  const void* A[4];
  unsigned long long bofs[4];
  float* C[4];
  unsigned short* P[4];
  unsigned short* P2[4];
  int ldc[4];
  int pldc[4];
  int p2ldc[4];
};

template <int BN, int BM, bool ABF>
__global__ __launch_bounds__(256) void gemm_mfma(
    GB gb, AUX aux, const unsigned short* __restrict__ Bth,
    int lda, int ldb, int M, int K,
    const float* __restrict__ bias, float fs, int flags) {
  constexpr int NSUB = BN / 32;
  constexpr int CPW = BN / 32;
  constexpr int MS = BM / 32;
  __shared__ __align__(16) unsigned short Ah[BM][64];
  __shared__ __align__(16) unsigned short Bh[BN][64];
  int xb = blockIdx.x;
  const int z = blockIdx.z;
  if (flags & 8) {
    if (xb < 938) { fill_body(xb + 938 * z, threadIdx.x, aux); return; }
    xb -= 938;
  }
  if (flags & 16) {
    if (xb < 3750) { llr_body(xb + 3750 * z, threadIdx.x, aux); return; }
    xb -= 3750;
  }
  const float* __restrict__ Af = (const float*)gb.A[z];
  const unsigned short* __restrict__ Ab = (const unsigned short*)gb.A[z];
  float* __restrict__ C = gb.C[z];
  unsigned short* __restrict__ P = gb.P[z];
  unsigned short* __restrict__ P2 = gb.P2[z];
  const int ldc = gb.ldc[z], pldc = gb.pldc[z], p2ldc = gb.p2ldc[z];
  const size_t bofs = gb.bofs[z];
  const int t = threadIdx.x;
  const int lane = t & 63, wv = t >> 6;
  const int lm = lane & 15, lg = lane >> 4;
  const int m0w = (wv & 1) * (BM / 2), n0w = (wv >> 1) * (BN / 2);
  const int row0 = xb * BM;
  f32x4 acc[MS][NSUB];
#pragma unroll
  for (int ms = 0; ms < MS; ms++)
#pragma unroll
    for (int ns = 0; ns < NSUB; ns++) acc[ms][ns] = (f32x4)0.f;

  float4 apre[MS][2];
  const int ar_ = t >> 3, ag_ = t & 7;

  auto loadA = [&](int k0) {
    if constexpr (!ABF) {
#pragma unroll
      for (int q = 0; q < MS; q++) {
        int rr = row0 + q * 32 + ar_;
        if (rr < M) {
          const float* p = Af + (size_t)rr * lda + k0 + ag_ * 8;
          apre[q][0] = *(const float4*)p;
          apre[q][1] = *(const float4*)(p + 4);
        } else {
          apre[q][0] = make_float4(0.f, 0.f, 0.f, 0.f);
          apre[q][1] = make_float4(0.f, 0.f, 0.f, 0.f);
        }
      }
    }
  };
  auto storeA = [&]() {
    if constexpr (!ABF) {
#pragma unroll
      for (int q = 0; q < MS; q++) {
        int r = q * 32 + ar_;
        us8 h8;
        float vals[8] = {apre[q][0].x, apre[q][0].y, apre[q][0].z, apre[q][0].w,
                         apre[q][1].x, apre[q][1].y, apre[q][1].z, apre[q][1].w};
#pragma unroll
        for (int e = 0; e < 8; e++) h8[e] = f2bf(vals[e]);
        int c = (ag_ ^ (r & 7)) << 3;
        *(us8*)&Ah[r][c] = h8;
      }
    }
  };
  auto stageA_bf = [&](int k0) {
    if constexpr (ABF) {
#pragma unroll
      for (int q = 0; q < MS; q++) {
        int r = q * 32 + ar_;
        int rr = min(row0 + r, M - 1);
        int scg = ag_ ^ (r & 7);
        gload16((char*)&Ah[0][0] + q * 4096 + t * 16,
                Ab + (size_t)rr * lda + k0 + scg * 8);
      }
    }
  };
  auto stageB = [&](int k0) {
#pragma unroll
    for (int q = 0; q < CPW; q++) {
      int chunk = wv * CPW + q;
      int o = chunk * 1024 + lane * 16;
      int n = o >> 7;
      int pq = (o >> 4) & 7;
      size_t gofs = bofs + (size_t)n * ldb + k0 + pq * 8;
      gload16((char*)&Bh[0][0] + o, Bth + gofs);
    }
  };

  loadA(0);
  for (int k0 = 0; k0 < K; k0 += 64) {
    if constexpr (ABF) stageA_bf(k0); else storeA();
    stageB(k0);
    __syncthreads();
    if constexpr (!ABF) { if (k0 + 64 < K) loadA(k0 + 64); }
#pragma unroll
    for (int kc = 0; kc < 2; kc++) {
      bf16x8 afh[MS], bfh[NSUB];
#pragma unroll
      for (int ms = 0; ms < MS; ms++) {
        int R = m0w + ms * 16 + lm;
        int c = (((kc * 4 + lg) ^ (R & 7)) << 3);
        afh[ms] = *(const bf16x8*)&Ah[R][c];
      }
#pragma unroll
      for (int ns = 0; ns < NSUB; ns++) {
        int R = n0w + ns * 16 + lm;
        int c = (((kc * 4 + lg) ^ (R & 7)) << 3);
        bfh[ns] = *(const bf16x8*)&Bh[R][c];
      }
#pragma unroll
      for (int ms = 0; ms < MS; ms++)
#pragma unroll
        for (int ns = 0; ns < NSUB; ns++)
          acc[ms][ns] = __builtin_amdgcn_mfma_f32_16x16x32_bf16(afh[ms], bfh[ns], acc[ms][ns], 0, 0, 0);
    }
    __syncthreads();
  }
#pragma unroll
  for (int ms = 0; ms < MS; ms++)
#pragma unroll
    for (int ns = 0; ns < NSUB; ns++)
#pragma unroll
      for (int j = 0; j < 4; j++) {
        int row = row0 + m0w + ms * 16 + lg * 4 + j;
        if (row >= M) continue;
        int col = n0w + ns * 16 + lm;
        float val = acc[ms][ns][j] * fs;
        if (bias) val += bias[col];
        if (flags & 2) val = (val > 0.f) ? val : NEG_OUT * val;
        unsigned short bv = f2bf(val);
        if (C) C[(size_t)row * ldc + col] = val;
        if (P) P[(size_t)row * pldc + col] = bv;
        if (P2) P2[(size_t)row * p2ldc + col] = bv;
      }
}

extern "C" void kernel_launch(void* const* d_in, const int* in_sizes, int n_in,
                              void* d_out, int out_size, void* d_ws, size_t ws_size,
                              hipStream_t stream) {
  const float* ft      = (const float*)d_in[0];
  const int*   src     = (const int*)  d_in[1];
  const int*   dst     = (const int*)  d_in[2];
  const float* W_proj  = (const float*)d_in[3];
  const float* W_embed = (const float*)d_in[4];
  const float* a_l     = (const float*)d_in[5];
  const float* a_r     = (const float*)d_in[6];
  const float* Wv      = (const float*)d_in[7];
  const float* Wgm     = (const float*)d_in[8];
  const float* Wgate   = (const float*)d_in[9];
  const float* b_gate  = (const float*)d_in[10];
  const float* W_tran  = (const float*)d_in[11];
  const float* b_tran  = (const float*)d_in[12];
  float* out = (float*)d_out;
  char* ws = (char*)d_ws;
  (void)in_sizes; (void)n_in; (void)out_size; (void)ws_size;

  size_t o = 0;
  auto take = [&](size_t bytes) { size_t r = o; o += (bytes + 255) & ~(size_t)255; return r; };
  int*   deg     = (int*)(ws + take((size_t)NV * NN * 4));
  int*   cursor  = (int*)(ws + take((size_t)NV * NN * 4));
  int*   csr_off = (int*)(ws + take((size_t)NV * (NN + 1) * 4));
  int*   csr_src = (int*)(ws + take((size_t)NV * EE * 4));
  int*   partial = (int*)(ws + take((size_t)NV * NCH * 4));
  float* Bl      = (float*)(ws + take((size_t)NV * NBLK * DD * NH * 4));
  float* Br      = (float*)(ws + take((size_t)NV * NBLK * DD * NH * 4));
  float* wf      = (float*)(ws + take((size_t)NV * 512 * 64 * 4));
  unsigned short* whi = (unsigned short*)(ws + take((size_t)WT_TOTAL * 2));
  unsigned short* hb  = (unsigned short*)(ws + take((size_t)NN * 640 * 2));  // [N,640] bf16
  unsigned short* pk0 = (unsigned short*)(ws + take((size_t)NN * 256 * 2));
  unsigned short* pk1 = (unsigned short*)(ws + take((size_t)NV * NN * 192 * 2));
  unsigned short* Sbf = (unsigned short*)(ws + take((size_t)NV * NN * 256 * 2));
  float4* lqb    = (float4*)(ws + take((size_t)NV * NN * 16));
  float2* lrb    = (float2*)(ws + take((size_t)NV * NN * 8));

  const int GMB = (NN + 127) / 128;  // 235

  hipMemsetAsync(deg, 0, (size_t)(((size_t)NV * NN * 4 + 255) & ~(size_t)255) + (size_t)NV * NN * 4, stream);
  kA_deg_prepw<<<2135, 256, 0, stream>>>(dst, deg, W_embed, a_l, a_r, W_proj, Wgm, Bl, Br, wf);
  kB_scan1_wsplit<<<1308, 256, 0, stream>>>(deg, partial, W_proj, wf, Wv, Wgm, W_tran, whi);
  k_scan3<<<NV * NCH, 256, 0, stream>>>(deg, partial, csr_off);

  // [fill ∥ proj GEMM]: proj writes pk0 (packed) + hb[:, 0:128]
  {
    GB gb = {};
    gb.A[0] = ft; gb.A[1] = ft;
    gb.bofs[0] = OFF_PROJVM; gb.bofs[1] = OFF_PROJVM + (size_t)128 * 512;
    gb.P[0] = pk0;        gb.pldc[0] = 256;
    gb.P2[0] = hb;        gb.p2ldc[0] = 640;
    gb.P[1] = pk0 + 128;  gb.pldc[1] = 256;
    AUX ax = {};
    ax.fsrc = src; ax.fdst = dst; ax.foff = csr_off; ax.fcur = cursor; ax.fcsr = csr_src;
    gemm_mfma<128, 128, false><<<dim3(938 + GMB, 1, 2), 256, 0, stream>>>(gb, ax, whi, IN_DIM, 512,
                                                                          NN, 512, nullptr, 1.f, 8);
  }

  // ---- layer 0 ----
  {
    AUX ax = {};
    ax.lp0 = pk0; ax.lp1 = pk0; ax.lps = 256;
    ax.lBl0 = Bl + 0 * 256; ax.lBr0 = Br + 0 * 256;
    ax.lBl1 = Bl + 2 * 256; ax.lBr1 = Br + 2 * 256;
    ax.lWg0 = Wgate; ax.lWg1 = Wgate + (size_t)NBLK * 320 * NH;
    ax.llq = lqb; ax.llr = lrb;
    k_llr<<<NN / 4, 256, 0, stream>>>(ax);
  }
  k_edge<<<dim3(NN / 4, 2), 256, 0, stream>>>(csr_off, csr_src, lqb, lrb,
                                              pk0, 0L, 256, 128, 64,
                                              Wgate, b_gate, Sbf);
  // mean merge -> pk1 v-part (bf16), K=256
  {
    GB gb = {};
    for (int j = 0; j < 2; j++) {
      gb.A[j] = Sbf + (size_t)j * NN * 256;
      gb.bofs[j] = OFF_WV + (size_t)(j * 2) * 32768;
      gb.P[j] = pk1 + (size_t)j * NN * 192;
      gb.pldc[j] = 192;
    }
    AUX ax = {};
    gemm_mfma<128, 128, true><<<dim3(GMB, 1, 2), 256, 0, stream>>>(gb, ax, whi, 256, 256, NN, 256,
                                                                   nullptr, 0.5f, 2);
  }
  // ---- layer 1: [vm GEMM ∥ llr1] ----
  {
    GB gb = {};
    for (int j = 0; j < 2; j++) {
      gb.A[j] = pk1 + (size_t)j * NN * 192;
      gb.bofs[j] = OFF_WGM + (size_t)j * 8192;
      gb.P[j] = pk1 + (size_t)j * NN * 192 + 128;
      gb.pldc[j] = 192;
    }
    AUX ax = {};
    ax.lp0 = pk1; ax.lp1 = pk1 + (size_t)NN * 192; ax.lps = 192;
    ax.lBl0 = Bl + 1 * 256; ax.lBr0 = Br + 1 * 256;
    ax.lBl1 = Bl + 3 * 256; ax.lBr1 = Br + 3 * 256;
    ax.lWg0 = Wgate + 640; ax.lWg1 = Wgate + (size_t)NBLK * 640 + 640;
    ax.llq = lqb; ax.llr = lrb;
    gemm_mfma<64, 128, true><<<dim3(3750 + GMB, 1, 2), 256, 0, stream>>>(gb, ax, whi, 192, 128,
                                                                         NN, 128, nullptr, 1.f, 16);
  }
  k_edge<<<dim3(NN / 4, 2), 256, 0, stream>>>(csr_off, csr_src, lqb, lrb,
                                              pk1, (long)NN * 192, 192, 128, 0,
                                              Wgate + 640, b_gate + NH, Sbf);
  // cat merge -> hb[:,128..640] bf16, per (view, head), K=128
  {
    GB gb = {};
    for (int z = 0; z < 4; z++) {
      int j = z >> 1, hd = z & 1;
      gb.A[z] = Sbf + (size_t)j * NN * 256 + hd * 128;
      gb.bofs[z] = OFF_WV + (size_t)(j * 2 + 1) * 32768 + hd * 128;
      gb.P[z] = hb + 128 + z * 128;
      gb.pldc[z] = 640;
    }
    AUX ax = {};
    gemm_mfma<128, 128, true><<<dim3(GMB, 1, 4), 256, 0, stream>>>(gb, ax, whi, 256, 256, NN, 128,
                                                                   nullptr, 1.f, 2);
  }
  // out = hb @ W_tran + b_tran  (bf16 A)
  {
    GB gb = {};
    gb.A[0] = hb; gb.bofs[0] = OFF_TRAN; gb.C[0] = out; gb.ldc[0] = OUTD;
    AUX ax = {};
    gemm_mfma<64, 128, true><<<dim3(GMB, 1, 1), 256, 0, stream>>>(gb, ax, whi, 640, 640, NN, 640,
                                                                  b_tran, 1.f, 0);
  }
}